// Round 1
// baseline (117.709 us; speedup 1.0000x reference)
//
#include <hip/hip_runtime.h>

// Radix2ModGroup: per 8-element group, quantize to int magnitude (SF=0.05,
// |q|<=255), keep the 12 largest-exponent power-of-two terms across the
// group's 64 (element,bit) candidates (ties -> lowest element index),
// reconstruct.
//
// R5 changes vs the 111.6us kernel:
//  - 2 groups (64 B) per thread: 4 float4 loads issued up front (2x memory
//    parallelism per thread), compute of group 0 overlaps the in-flight
//    loads of group 1. Grid halves (4096 blocks of 256).
//  - fabs-first quantization: round(|x|/SF) == |round(x/SF)| since RTNE and
//    the exact-division Markstein sequence are both sign-symmetric. fabs is
//    a free input modifier, clamp collapses to one v_min_f32, and the
//    integer abs/negation handling disappears (~3 VALU ops/elem saved).
//
// Retained from previous rounds (do not revert):
//  - contiguous float4 loads/stores; nontemporal hints measured SLOWER.
//  - branchless selection: pack 8 magnitudes into a uint64, 8x8
//    bit-transpose so bit position 8*e + (7-i) is a strict priority
//    (exponent major, low element index minor) -> "top-12 terms" ==
//    "top-12 set bits" (branchless rank-select).
//  - x/0.05f bit-exact via Markstein: RN(1/0.05f) == 20.0f exactly, so
//    q0 = m*20; r = fma(-0.05,q0,m); q = fma(r,20,q0) is the correctly
//    rounded IEEE quotient for all normal-range inputs. Validated absmax 0.

constexpr float SF = 0.05f;
constexpr float RCP = 20.0f;   // RN(1 / 0.05f) == 20.0f exactly
constexpr int NUM_EXPS = 12;

__device__ __forceinline__ unsigned long long transpose8x8(unsigned long long x) {
  // bit(8r+c) <-> bit(8c+r)  (Hacker's Delight 8x8 bit-matrix transpose)
  unsigned long long t;
  t = (x ^ (x >> 7)) & 0x00AA00AA00AA00AAull; x ^= t ^ (t << 7);
  t = (x ^ (x >> 14)) & 0x0000CCCC0000CCCCull; x ^= t ^ (t << 14);
  t = (x ^ (x >> 28)) & 0x00000000F0F0F0F0ull; x ^= t ^ (t << 28);
  return x;
}

__device__ __forceinline__ void process_group(const float v[8], float o[8]) {
  // Quantize |v|; pack magnitude of element i into byte (7-i) of M.
  unsigned long long M = 0ull;
#pragma unroll
  for (int i = 0; i < 8; ++i) {
    float m  = __builtin_fabsf(v[i]);          // free input modifier
    float q0 = m * RCP;
    float r0 = __builtin_fmaf(-SF, q0, m);
    float q  = __builtin_fmaf(r0, RCP, q0);    // == |v[i]| / 0.05f, exact
    float r  = fminf(rintf(q), 255.0f);        // RTNE == jnp.round; q >= 0
    unsigned mi = (unsigned)r;                 // exact, in [0,255]
    M |= (unsigned long long)mi << (8 * (7 - i));
  }

  // w bit (8e + (7-i)) = bit e of mag_i. Position = selection priority.
  unsigned long long w = transpose8x8(M);

  // Drop the jj = max(P-12, 0) lowest-priority set bits.
  int P = __popcll(w);
  int jj = P > NUM_EXPS ? P - NUM_EXPS : 0;

  // Branchless rank-select: pos = index of the (jj+1)-th set bit from LSB.
  unsigned long long xx = w;
  int pos = 0;
  int c;
  c = __popcll(xx & 0xffffffffull);
  { int s = (jj >= c); pos += s << 5; jj -= s ? c : 0; xx = s ? (xx >> 32) : xx; }
  c = __popc((unsigned)xx & 0xffffu);
  { int s = (jj >= c); pos += s << 4; jj -= s ? c : 0; xx = s ? (xx >> 16) : xx; }
  c = __popc((unsigned)xx & 0xffu);
  { int s = (jj >= c); pos += s << 3; jj -= s ? c : 0; xx = s ? (xx >> 8) : xx; }
  c = __popc((unsigned)xx & 0xfu);
  { int s = (jj >= c); pos += s << 2; jj -= s ? c : 0; xx = s ? (xx >> 4) : xx; }
  c = __popc((unsigned)xx & 0x3u);
  { int s = (jj >= c); pos += s << 1; jj -= s ? c : 0; xx = s ? (xx >> 2) : xx; }
  c = (int)((unsigned)xx & 1u);
  { int s = (jj >= c); pos += s; }

  unsigned long long keep = w & (~0ull << pos);

  // Transpose back: byte (7-i) of Kt = kept magnitude of element i.
  unsigned long long Kt = transpose8x8(keep);

#pragma unroll
  for (int i = 0; i < 8; ++i) {
    unsigned mi = (unsigned)(Kt >> (8 * (7 - i))) & 0xffu;
    // sign of q == sign of x whenever mag != 0; mag==0 -> +/-0 == 0.
    o[i] = copysignf((float)mi * SF, v[i]);
  }
}

__global__ __launch_bounds__(256) void radix2_mod_group_kernel(
    const float4* __restrict__ xv, float4* __restrict__ ov) {
  int t = blockIdx.x * blockDim.x + threadIdx.x;  // grid divides exactly

  // 2 groups = 4 contiguous float4 (64 B) per thread; all 4 loads issue
  // before any compute (compiler waits vmcnt as operands are consumed).
  float4 a0 = xv[4 * t + 0];
  float4 a1 = xv[4 * t + 1];
  float4 a2 = xv[4 * t + 2];
  float4 a3 = xv[4 * t + 3];

  float v0[8] = {a0.x, a0.y, a0.z, a0.w, a1.x, a1.y, a1.z, a1.w};
  float v1[8] = {a2.x, a2.y, a2.z, a2.w, a3.x, a3.y, a3.z, a3.w};

  float o0[8], o1[8];
  process_group(v0, o0);
  ov[4 * t + 0] = make_float4(o0[0], o0[1], o0[2], o0[3]);
  ov[4 * t + 1] = make_float4(o0[4], o0[5], o0[6], o0[7]);
  process_group(v1, o1);
  ov[4 * t + 2] = make_float4(o1[0], o1[1], o1[2], o1[3]);
  ov[4 * t + 3] = make_float4(o1[4], o1[5], o1[6], o1[7]);
}

extern "C" void kernel_launch(void* const* d_in, const int* in_sizes, int n_in,
                              void* d_out, int out_size, void* d_ws, size_t ws_size,
                              hipStream_t stream) {
  const float* x = (const float*)d_in[0];
  float* out = (float*)d_out;
  int n = in_sizes[0];            // elements: 16,777,216 for 4096x4096
  int nthreads = n / 16;          // 2 groups (16 elems) per thread
  int block = 256;
  int grid = nthreads / block;    // 4096; divides exactly, no tail guard
  radix2_mod_group_kernel<<<grid, block, 0, stream>>>(
      (const float4*)x, (float4*)out);
}

// Round 2
// 109.038 us; speedup vs baseline: 1.0795x; 1.0795x over previous
//
#include <hip/hip_runtime.h>

// Radix2ModGroup: per 8-element group, quantize to int magnitude (SF=0.05,
// |q|<=255), keep the 12 largest-exponent power-of-two terms across the
// group's 64 (element,bit) candidates (ties -> lowest element index),
// reconstruct.
//
// R6: fully-coalesced memory at 16B lane stride + shfl redistribution.
//   Evidence: R0 (32B/lane stride) kernel ~28.4us, R5 (64B stride) ~34.7us
//   -> per-line request count is the bottleneck (2 req/line vs 4 req/line;
//   +3.2us per extra request/line). This version issues all global loads
//   and stores at 16B lane stride (1 req/line, the float4-copy pattern that
//   hits 6.3 TB/s) and redistributes lane<->group ownership with __shfl
//   (ds_bpermute on the otherwise-idle LDS pipe, 32 ops/thread).
//   1 group/thread (R5's 2 groups/thread regressed; do not re-widen).
//
// Wave layout: wave w owns float4 indices [128w, 128w+128) = groups
// [64w, 64w+64). Load: lane l grabs float4 128w+l (rA) and 128w+64+l (rB).
// Lane l processes group 64w+l, whose data is float4s 2l, 2l+1 of the wave
// region: pulled from source lane s0=(2l)&63 / s0+1, register rA if l<32
// else rB. Store mirrors: lane l writes float4 l (half l&1 of group l>>1,
// pulled from lane l>>1) and float4 64+l (from lane 32+(l>>1)).
//
// Retained from previous rounds (do not revert):
//  - fabs-first quantization: round(|x|/SF) == |round(x/SF)| (RTNE and the
//    Markstein sequence are sign-symmetric); clamp is one v_min_f32.
//    Validated absmax 0 in R5.
//  - branchless selection: pack 8 magnitudes into a uint64, 8x8
//    bit-transpose so bit position 8*e + (7-i) is a strict priority
//    (exponent major, low element index minor) -> "top-12 terms" ==
//    "top-12 set bits" (branchless rank-select).
//  - x/0.05f bit-exact via Markstein: RN(1/0.05f) == 20.0f exactly, so
//    q0 = m*20; r = fma(-0.05,q0,m); q = fma(r,20,q0) is the correctly
//    rounded IEEE quotient for all normal-range inputs. Validated absmax 0.
//  - nontemporal hints measured SLOWER on gfx950; do not re-add.

constexpr float SF = 0.05f;
constexpr float RCP = 20.0f;   // RN(1 / 0.05f) == 20.0f exactly
constexpr int NUM_EXPS = 12;

__device__ __forceinline__ unsigned long long transpose8x8(unsigned long long x) {
  // bit(8r+c) <-> bit(8c+r)  (Hacker's Delight 8x8 bit-matrix transpose)
  unsigned long long t;
  t = (x ^ (x >> 7)) & 0x00AA00AA00AA00AAull; x ^= t ^ (t << 7);
  t = (x ^ (x >> 14)) & 0x0000CCCC0000CCCCull; x ^= t ^ (t << 14);
  t = (x ^ (x >> 28)) & 0x00000000F0F0F0F0ull; x ^= t ^ (t << 28);
  return x;
}

__device__ __forceinline__ void process_group(const float v[8], float o[8]) {
  // Quantize |v|; pack magnitude of element i into byte (7-i) of M.
  unsigned long long M = 0ull;
#pragma unroll
  for (int i = 0; i < 8; ++i) {
    float m  = __builtin_fabsf(v[i]);          // free input modifier
    float q0 = m * RCP;
    float r0 = __builtin_fmaf(-SF, q0, m);
    float q  = __builtin_fmaf(r0, RCP, q0);    // == |v[i]| / 0.05f, exact
    float r  = fminf(rintf(q), 255.0f);        // RTNE == jnp.round; q >= 0
    unsigned mi = (unsigned)r;                 // exact, in [0,255]
    M |= (unsigned long long)mi << (8 * (7 - i));
  }

  // w bit (8e + (7-i)) = bit e of mag_i. Position = selection priority.
  unsigned long long w = transpose8x8(M);

  // Drop the jj = max(P-12, 0) lowest-priority set bits.
  int P = __popcll(w);
  int jj = P > NUM_EXPS ? P - NUM_EXPS : 0;

  // Branchless rank-select: pos = index of the (jj+1)-th set bit from LSB.
  unsigned long long xx = w;
  int pos = 0;
  int c;
  c = __popcll(xx & 0xffffffffull);
  { int s = (jj >= c); pos += s << 5; jj -= s ? c : 0; xx = s ? (xx >> 32) : xx; }
  c = __popc((unsigned)xx & 0xffffu);
  { int s = (jj >= c); pos += s << 4; jj -= s ? c : 0; xx = s ? (xx >> 16) : xx; }
  c = __popc((unsigned)xx & 0xffu);
  { int s = (jj >= c); pos += s << 3; jj -= s ? c : 0; xx = s ? (xx >> 8) : xx; }
  c = __popc((unsigned)xx & 0xfu);
  { int s = (jj >= c); pos += s << 2; jj -= s ? c : 0; xx = s ? (xx >> 4) : xx; }
  c = __popc((unsigned)xx & 0x3u);
  { int s = (jj >= c); pos += s << 1; jj -= s ? c : 0; xx = s ? (xx >> 2) : xx; }
  c = (int)((unsigned)xx & 1u);
  { int s = (jj >= c); pos += s; }

  unsigned long long keep = w & (~0ull << pos);

  // Transpose back: byte (7-i) of Kt = kept magnitude of element i.
  unsigned long long Kt = transpose8x8(keep);

#pragma unroll
  for (int i = 0; i < 8; ++i) {
    unsigned mi = (unsigned)(Kt >> (8 * (7 - i))) & 0xffu;
    // sign of q == sign of x whenever mag != 0; mag==0 -> +/-0 == 0.
    o[i] = copysignf((float)mi * SF, v[i]);
  }
}

__global__ __launch_bounds__(256) void radix2_mod_group_kernel(
    const float4* __restrict__ xv, float4* __restrict__ ov) {
  int t = blockIdx.x * blockDim.x + threadIdx.x;  // grid divides exactly
  int lane = threadIdx.x & 63;
  int wid = t >> 6;

  const float4* ibase = xv + (size_t)wid * 128;
  float4* obase = ov + (size_t)wid * 128;

  // Perfectly coalesced loads: 16B lane stride, 1 request per 64B line.
  float4 rA = ibase[lane];
  float4 rB = ibase[64 + lane];

  // Redistribute: lane l <- float4s 2l, 2l+1 of the wave region.
  int s0 = (2 * lane) & 63;   // source lane for first float4
  int s1 = s0 + 1;            // source lane for second float4
  bool lo = (lane < 32);      // source register: rA if lane<32 else rB

  float v[8];
  {
    float ax = __shfl(rA.x, s0), bx = __shfl(rB.x, s0);
    float ay = __shfl(rA.y, s0), by = __shfl(rB.y, s0);
    float az = __shfl(rA.z, s0), bz = __shfl(rB.z, s0);
    float aw = __shfl(rA.w, s0), bw = __shfl(rB.w, s0);
    v[0] = lo ? ax : bx;
    v[1] = lo ? ay : by;
    v[2] = lo ? az : bz;
    v[3] = lo ? aw : bw;
  }
  {
    float ax = __shfl(rA.x, s1), bx = __shfl(rB.x, s1);
    float ay = __shfl(rA.y, s1), by = __shfl(rB.y, s1);
    float az = __shfl(rA.z, s1), bz = __shfl(rB.z, s1);
    float aw = __shfl(rA.w, s1), bw = __shfl(rB.w, s1);
    v[4] = lo ? ax : bx;
    v[5] = lo ? ay : by;
    v[6] = lo ? az : bz;
    v[7] = lo ? aw : bw;
  }

  float o[8];
  process_group(v, o);

  // Redistribute back for perfectly coalesced stores.
  // float4 index l     = half (l&1) of group l>>1       (source lane l>>1)
  // float4 index 64+l  = half (l&1) of group 32+(l>>1)  (source lane 32+(l>>1))
  int m1 = lane >> 1;
  int m2 = 32 + m1;
  bool hi = (lane & 1);

  float4 S1, S2;
  {
    float l0 = __shfl(o[0], m1), h0 = __shfl(o[4], m1);
    float l1 = __shfl(o[1], m1), h1 = __shfl(o[5], m1);
    float l2 = __shfl(o[2], m1), h2 = __shfl(o[6], m1);
    float l3 = __shfl(o[3], m1), h3 = __shfl(o[7], m1);
    S1.x = hi ? h0 : l0;
    S1.y = hi ? h1 : l1;
    S1.z = hi ? h2 : l2;
    S1.w = hi ? h3 : l3;
  }
  {
    float l0 = __shfl(o[0], m2), h0 = __shfl(o[4], m2);
    float l1 = __shfl(o[1], m2), h1 = __shfl(o[5], m2);
    float l2 = __shfl(o[2], m2), h2 = __shfl(o[6], m2);
    float l3 = __shfl(o[3], m2), h3 = __shfl(o[7], m2);
    S2.x = hi ? h0 : l0;
    S2.y = hi ? h1 : l1;
    S2.z = hi ? h2 : l2;
    S2.w = hi ? h3 : l3;
  }

  // Perfectly coalesced stores: 16B lane stride.
  obase[lane] = S1;
  obase[64 + lane] = S2;
}

extern "C" void kernel_launch(void* const* d_in, const int* in_sizes, int n_in,
                              void* d_out, int out_size, void* d_ws, size_t ws_size,
                              hipStream_t stream) {
  const float* x = (const float*)d_in[0];
  float* out = (float*)d_out;
  int n = in_sizes[0];            // elements: 16,777,216 for 4096x4096
  int ngroups = n / 8;            // 2,097,152 groups, 1 per thread
  int block = 256;
  int grid = ngroups / block;     // 8192; divides exactly, no tail guard
  radix2_mod_group_kernel<<<grid, block, 0, stream>>>(
      (const float4*)x, (float4*)out);
}